// Round 15
// baseline (190.456 us; speedup 1.0000x reference)
//
#include <hip/hip_runtime.h>
#include <cstdint>
#include <cstddef>

// Problem constants (B,S,D,H) = (2, 2048, 256, 8)
#define S_LEN 2048
#define DIM   256
#define NH    8
#define NB    2
#define HDIM  (NH * DIM)   // 2048

using bf16 = __bf16;
typedef __bf16 bf16x8 __attribute__((ext_vector_type(8)));
typedef __bf16 bf16x4 __attribute__((ext_vector_type(4)));
typedef float  f32x4  __attribute__((ext_vector_type(4)));

typedef const __attribute__((address_space(1))) unsigned int* as1_u32p;
typedef __attribute__((address_space(3))) unsigned int* as3_u32p;

// async 16B global -> LDS (no VGPR round-trip). LDS dest = wave-uniform base
// + lane*16 (m104/m108).
__device__ __forceinline__ void cp16(const bf16* g, bf16* l) {
    __builtin_amdgcn_global_load_lds((as1_u32p)g, (as3_u32p)l, 16, 0, 0);
}

// ---------------------------------------------------------------------------
// Fused prep (one launch): z=0..2 -> wQ/wK/wV transpose-cast (h = y>>2),
// z=3 -> wO transpose-cast, z=4 -> X fp32->bf16 cast. grid dim3(4,32,5).
// ---------------------------------------------------------------------------
__global__ __launch_bounds__(256) void prep_kernel(const float* __restrict__ X,
                                                   const float* __restrict__ wQ,
                                                   const float* __restrict__ wK,
                                                   const float* __restrict__ wV,
                                                   const float* __restrict__ wO,
                                                   bf16* __restrict__ Xb,
                                                   bf16* __restrict__ WQt,
                                                   bf16* __restrict__ WKt,
                                                   bf16* __restrict__ WVt,
                                                   bf16* __restrict__ WOt)
{
    const int z = blockIdx.z;
    if (z == 4) {                     // cast X
        const int t = (blockIdx.y*4 + blockIdx.x)*256 + threadIdx.x;   // 0..32767
        #pragma unroll
        for (int p = 0; p < 8; ++p) {
            const int i = (t + p*32768)*4;
            float4 v = *(const float4*)(X + i);
            bf16x4 o;
            o[0] = (bf16)v.x; o[1] = (bf16)v.y; o[2] = (bf16)v.z; o[3] = (bf16)v.w;
            *(bf16x4*)(Xb + i) = o;
        }
        return;
    }
    __shared__ float tile[64][65];
    const float* in; bf16* out; int R, C, r0, c0;
    if (z < 3) {
        const int h = blockIdx.y >> 2;
        in  = (z == 0 ? wQ : z == 1 ? wK : wV) + (size_t)h * DIM * DIM;
        out = (z == 0 ? WQt : z == 1 ? WKt : WVt) + (size_t)h * DIM * DIM;
        R = DIM; C = DIM; r0 = (blockIdx.y & 3) * 64; c0 = blockIdx.x * 64;
    } else {
        in = wO; out = WOt; R = HDIM; C = DIM;
        r0 = blockIdx.y * 64; c0 = blockIdx.x * 64;
    }
    const int tr  = threadIdx.x >> 4;
    const int tc4 = (threadIdx.x & 15) * 4;
    #pragma unroll
    for (int p = 0; p < 4; ++p) {
        int row = p * 16 + tr;
        float4 v = *(const float4*)(in + (size_t)(r0 + row) * C + c0 + tc4);
        tile[row][tc4+0] = v.x; tile[row][tc4+1] = v.y;
        tile[row][tc4+2] = v.z; tile[row][tc4+3] = v.w;
    }
    __syncthreads();
    #pragma unroll
    for (int p = 0; p < 4; ++p) {
        int orow = p * 16 + tr;
        bf16x4 o;
        #pragma unroll
        for (int j = 0; j < 4; ++j) o[j] = (bf16)tile[tc4 + j][orow];
        *(bf16x4*)(out + (size_t)(c0 + orow) * R + r0 + tc4) = o;
    }
}

// ---------------------------------------------------------------------------
// 128x256-tile bf16 MFMA GEMM, 512 threads (8 waves in 2x4), BK=32.
// R8-verified staging/swizzle/1-barrier schedule, scaled up: 24 KB staged
// per k-step feeds 128 MFMAs (192 B/MFMA vs 256 in the 128x128 version).
// LDS: As 2x(128x32)=16KB + Bs 2x(256x32)=32KB = 48 KB.
// EPI: 0 = bf16 store, 1 = f32 store.
// ---------------------------------------------------------------------------
template<int EPI>
__device__ __forceinline__ void gemm512(const bf16* __restrict__ A, const bf16* __restrict__ BT,
                                        void* __restrict__ C, bf16* As, bf16* Bs,
                                        int tm, int tn, int K, int lda, int ldb, int ldc)
{
    const int tid  = threadIdx.x;      // 0..511
    const int lane = tid & 63;
    const int w    = tid >> 6;         // 0..7
    const int wm   = (w >> 2) << 6;    // 0 | 64
    const int wn   = (w & 3) << 6;     // 0..192
    const int l16  = lane & 15;
    const int quad = lane >> 4;

    const int m0 = tm << 7, n0 = tn << 8;

    // A: 512 16B-chunks (128x32), wave w stages chunks w*64+lane (1 instr)
    // B: 1024 chunks (256x32), wave w stages (w*2+j)*64+lane, j=0,1
    // chunk c -> row=c>>2, pos=c&3, holds global chunk (c&3)^(row&3)
    const int ca = (w << 6) + lane;
    const int ra = ca >> 2, ga = (ca & 3) ^ ((ca >> 2) & 3);

    f32x4 acc[4][4] = {};
    const int ksteps = K >> 5;

    // prologue: stage k-step 0 into buf 0
    cp16(A + (size_t)(m0 + ra)*lda + (ga << 3), As + (w << 9));
    #pragma unroll
    for (int j = 0; j < 2; ++j) {
        const int cb = ((w*2 + j) << 6) + lane;
        const int rb = cb >> 2, gb = (cb & 3) ^ (rb & 3);
        cp16(BT + (size_t)(n0 + rb)*ldb + (gb << 3), Bs + ((w*2 + j) << 9));
    }

    for (int ks = 0; ks < ksteps; ++ks) {
        const int pb = ks & 1;
        asm volatile("s_waitcnt vmcnt(0)" ::: "memory");
        __syncthreads();
        if (ks + 1 < ksteps) {
            const int k1 = (ks + 1) << 5;
            cp16(A + (size_t)(m0 + ra)*lda + k1 + (ga << 3),
                 As + (pb ^ 1)*4096 + (w << 9));
            #pragma unroll
            for (int j = 0; j < 2; ++j) {
                const int cb = ((w*2 + j) << 6) + lane;
                const int rb = cb >> 2, gb = (cb & 3) ^ (rb & 3);
                cp16(BT + (size_t)(n0 + rb)*ldb + k1 + (gb << 3),
                     Bs + (pb ^ 1)*8192 + ((w*2 + j) << 9));
            }
        }
        const bf16* Ab = As + pb*4096;
        const bf16* Bb = Bs + pb*8192;
        bf16x8 af[4], bfv[4];
        #pragma unroll
        for (int i = 0; i < 4; ++i) {
            const int row = wm + i*16 + l16;
            af[i] = *(const bf16x8*)(Ab + row*32 + ((quad ^ (l16 & 3)) << 3));
        }
        #pragma unroll
        for (int i = 0; i < 4; ++i) {
            const int row = wn + i*16 + l16;
            bfv[i] = *(const bf16x8*)(Bb + row*32 + ((quad ^ (l16 & 3)) << 3));
        }
        #pragma unroll
        for (int i = 0; i < 4; ++i)
            #pragma unroll
            for (int j = 0; j < 4; ++j)
                acc[i][j] = __builtin_amdgcn_mfma_f32_16x16x32_bf16(af[i], bfv[j], acc[i][j], 0, 0, 0);
    }

    #pragma unroll
    for (int i = 0; i < 4; ++i)
        #pragma unroll
        for (int j = 0; j < 4; ++j)
            #pragma unroll
            for (int r = 0; r < 4; ++r) {
                int mg = m0 + wm + i*16 + quad*4 + r;
                int ng = n0 + wn + j*16 + l16;
                float v = acc[i][j][r];
                if (EPI == 0) ((bf16*)C)[(size_t)mg * ldc + ng] = (bf16)v;
                else          ((float*)C)[(size_t)mg * ldc + ng] = v;
            }
}

// QKV projections, 512-thread tiles. grid = (16, 48):
//   y<32:  mat = y>>4 (Q|K), bh = y&15 : tile (x, 0) of X[b] @ W[h]   (N=256)
//   y>=32: bh = y-32          : tile (x&1, x>>1) of WVt[h] @ Xb[b]^T  (VT)
__global__ __launch_bounds__(512) void proj_kernel(const bf16* __restrict__ Xb,
    const bf16* __restrict__ WQt, const bf16* __restrict__ WKt, const bf16* __restrict__ WVt,
    bf16* __restrict__ Qg, bf16* __restrict__ Kg, bf16* __restrict__ VTg)
{
    __shared__ __align__(16) bf16 smem[3 * 8192];   // As 2x4096 | Bs 2x8192
    const int y = blockIdx.y, x = blockIdx.x;
    if (y < 32) {
        const int mat = y >> 4, bh = y & 15;
        const int b = bh >> 3, h = bh & 7;
        const bf16* W = (mat ? WKt : WQt) + (size_t)h*DIM*DIM;
        bf16*      Cg = (mat ? Kg  : Qg ) + (size_t)bh*S_LEN*DIM;
        gemm512<0>(Xb + (size_t)b*S_LEN*DIM, W, Cg, smem, smem + 8192,
                   x, 0, DIM, DIM, DIM, DIM);
    } else {
        const int bh = y - 32;
        const int b = bh >> 3, h = bh & 7;
        gemm512<0>(WVt + (size_t)h*DIM*DIM, Xb + (size_t)b*S_LEN*DIM,
                   VTg + (size_t)bh*DIM*S_LEN, smem, smem + 8192,
                   x & 1, x >> 1, DIM, DIM, DIM, S_LEN);
    }
}

// outproj: 8-way K-split into fp32 slabs. grid 256: tm = bx&31, kq = bx>>5.
__global__ __launch_bounds__(512) void outproj_kernel(const bf16* __restrict__ Ret,
                                                      const bf16* __restrict__ WOt,
                                                      float* __restrict__ slabs)
{
    __shared__ __align__(16) bf16 smem[3 * 8192];
    const int tm = blockIdx.x & 31, kq = blockIdx.x >> 5;
    gemm512<1>(Ret + kq*256, WOt + kq*256, slabs + (size_t)kq*4096*256,
               smem, smem + 8192, tm, 0, 256, HDIM, HDIM, DIM);
}

// sum 8 slabs -> d_out. 1024 blocks x 256 thr x float4.
__global__ __launch_bounds__(256) void reduce_out_kernel(const float* __restrict__ slabs,
                                                         float* __restrict__ out)
{
    const size_t i = ((size_t)blockIdx.x*256 + threadIdx.x)*4;
    const size_t N = (size_t)4096*256;
    float4 w = *(const float4*)(slabs + i);
    #pragma unroll
    for (int s = 1; s < 8; ++s) {
        float4 a = *(const float4*)(slabs + (size_t)s*N + i);
        w.x += a.x; w.y += a.y; w.z += a.z; w.w += a.w;
    }
    *(float4*)(out + i) = w;
}

// ---------------------------------------------------------------------------
// Split-K flash causal attention — ROUND-14-verified, byte-identical.
// ---------------------------------------------------------------------------
__global__ __launch_bounds__(256, 2) void attn_kernel(const bf16* __restrict__ Qg,
                                                      const bf16* __restrict__ Kg,
                                                      const bf16* __restrict__ VTg,
                                                      bf16* __restrict__ Ret,
                                                      bf16* __restrict__ Opart,
                                                      float* __restrict__ Lpart)
{
    __shared__ __align__(16) bf16 Ks [64 * 256];   // 32 KB, swizzle c^(row&31)
    __shared__ __align__(16) bf16 VTs[256 * 64];   // 32 KB, swizzle c^(e&7)
    __shared__ __align__(16) bf16 Ps [64 * 72];    // 9 KB, padded

    static const unsigned char order[63] = {
        10,29,31,32,57,60,61,
        9,25,27,28,30,48,51,52,54,55,56,58,59,62,
        8,21,23,24,26,39,42,43,45,46,47,49,50,53,
        7,17,19,20,22,33,34,36,37,38,40,41,44,
        6,13,15,16,18,35,
        5,11,12,14,
        4,3,2,1,0 };

    const int tid  = threadIdx.x;
    const int lane = tid & 63;
    const int wave = tid >> 6;
    const int l16  = lane & 15;
    const int quad = lane >> 4;
    const int cw   = wave << 6;            // PV col strip

    const int bx  = blockIdx.x;                      // 0..1007
    const int bh  = bx & 15;
    const int bid = order[bx >> 4];                  // 0..62
    int qt, s, nsp;
    if (bid <= 10)      { qt = bid;                    s = 0;       nsp = 1; }
    else if (bid <= 32) { int k = bid - 11; qt = 11 + (k >> 1); s = k & 1; nsp = 2; }
    else                { int k = bid - 33; int q3 = k / 3; qt = 22 + q3; s = k - 3*q3; nsp = 3; }
    const int b = bh >> 3, h = bh & 7;

    const int S2 = qt + 1;                 // total 64-key steps
    const int base = S2 / nsp, rem = S2 - nsp*base;
    const int kstep0 = s*base + (s < rem ? s : rem);
    const int kstep1 = kstep0 + base + (s < rem ? 1 : 0);

    const bf16* Qbh  = Qg  + (size_t)(b*NH + h) * S_LEN * DIM;
    const bf16* Kbh  = Kg  + (size_t)(b*NH + h) * S_LEN * DIM;
    const bf16* VTbh = VTg + (size_t)(b*NH + h) * DIM * S_LEN;

    const int qbase = qt*64 + wave*16;     // QK: this wave's 16 rows

    bf16x8 qf[8];
    #pragma unroll
    for (int kc = 0; kc < 8; ++kc)
        qf[kc] = *(const bf16x8*)(Qbh + (size_t)(qbase + l16)*DIM + kc*32 + quad*8);

    f32x4 o[16] = {};                      // [rt*4+ct]: 64 rows x 64 cols (strip)
    float l_part[4] = {0.f, 0.f, 0.f, 0.f};

    {
        const int t00 = kstep0 << 6;
        #pragma unroll
        for (int j = 0; j < 8; ++j) {
            const int sN = ((wave*8 + j) << 6) + lane;
            const int ts = sN >> 5, cs = sN & 31;
            cp16(Kbh + (size_t)(t00 + ts)*DIM + ((cs ^ (ts & 31)) << 3),
                 Ks + ((wave*8 + j) << 9));
        }
    }

    for (int step = kstep0; step < kstep1; ++step) {
        const int t0 = step << 6;
        asm volatile("s_barrier" ::: "memory");
        #pragma unroll
        for (int j = 0; j < 8; ++j) {
            const int sN = ((wave*8 + j) << 6) + lane;
            const int es = sN >> 3, cs = sN & 7;
            cp16(VTbh + (size_t)es*S_LEN + t0 + ((cs ^ (es & 7)) << 3),
                 VTs + ((wave*8 + j) << 9));
        }
        asm volatile("s_waitcnt vmcnt(8)\n\ts_barrier" ::: "memory");

        f32x4 sacc[4] = {};
        #pragma unroll
        for (int kc = 0; kc < 8; ++kc) {
            const int ch = (kc << 2) + quad;
            #pragma unroll
            for (int kt = 0; kt < 4; ++kt) {
                const int row = kt*16 + l16;
                bf16x8 kf = *(const bf16x8*)(Ks + row*256 + ((ch ^ (row & 31)) << 3));
                sacc[kt] = __builtin_amdgcn_mfma_f32_16x16x32_bf16(qf[kc], kf, sacc[kt], 0,0,0);
            }
        }

        #pragma unroll
        for (int kt = 0; kt < 4; ++kt) {
            const int tg = t0 + kt*16 + l16;
            #pragma unroll
            for (int r = 0; r < 4; ++r) {
                const int qgi = qbase + quad*4 + r;
                float p = (tg <= qgi) ? __expf(sacc[kt][r] * 0.0625f) : 0.0f;
                l_part[r] += p;
                Ps[(wave*16 + quad*4 + r)*72 + kt*16 + l16] = (bf16)p;
            }
        }
        __syncthreads();

        if (step + 1 < kstep1) {
            const int t1 = (step + 1) << 6;
            #pragma unroll
            for (int j = 0; j < 8; ++j) {
                const int sN = ((wave*8 + j) << 6) + lane;
                const int ts = sN >> 5, cs = sN & 31;
                cp16(Kbh + (size_t)(t1 + ts)*DIM + ((cs ^ (ts & 31)) << 3),
                     Ks + ((wave*8 + j) << 9));
            }
        }

        #pragma unroll
        for (int kc2 = 0; kc2 < 2; ++kc2) {
            bf16x8 pf[4];
            #pragma unroll
            for (int rt = 0; rt < 4; ++rt)
                pf[rt] = *(const bf16x8*)(Ps + (rt*16 + l16)*72 + kc2*32 + quad*8);
            #pragma unroll
            for (int ct = 0; ct < 4; ++ct) {
                const int e = cw + ct*16 + l16;
                const int g = (kc2 << 2) + quad;
                bf16x8 vf = *(const bf16x8*)(VTs + e*64 + ((g ^ (e & 7)) << 3));
                #pragma unroll
                for (int rt = 0; rt < 4; ++rt)
                    o[rt*4 + ct] = __builtin_amdgcn_mfma_f32_16x16x32_bf16(pf[rt], vf, o[rt*4 + ct], 0,0,0);
            }
        }
    }

    float lsum[4];
    #pragma unroll
    for (int r = 0; r < 4; ++r) {
        float l = l_part[r];
        l += __shfl_xor(l, 1);
        l += __shfl_xor(l, 2);
        l += __shfl_xor(l, 4);
        l += __shfl_xor(l, 8);
        lsum[r] = l;
    }

    __syncthreads();
    float* Lp = (float*)Ps;
    if (l16 == 0) {
        #pragma unroll
        for (int r = 0; r < 4; ++r) Lp[wave*16 + quad*4 + r] = lsum[r];
    }
    __syncthreads();

    if (nsp == 1) {
        #pragma unroll
        for (int rt = 0; rt < 4; ++rt)
            #pragma unroll
            for (int r = 0; r < 4; ++r) {
                const int row = rt*16 + quad*4 + r;
                const float inv = 1.0f / Lp[row];
                #pragma unroll
                for (int ct = 0; ct < 4; ++ct)
                    Ret[((size_t)b*S_LEN + qt*64 + row)*HDIM + h*DIM + cw + ct*16 + l16]
                        = (bf16)(o[rt*4 + ct][r] * inv);
            }
    } else {
        const int slotbase = (qt <= 21) ? ((qt - 11)*2 + s) : (22 + (qt - 22)*3 + s);
        const size_t slot = (size_t)bh*52 + slotbase;
        bf16*  Ob = Opart + slot * (64*256);
        float* Lb = Lpart + slot * 64;
        if (l16 == 0) {
            #pragma unroll
            for (int r = 0; r < 4; ++r) Lb[wave*16 + quad*4 + r] = lsum[r];
        }
        #pragma unroll
        for (int rt = 0; rt < 4; ++rt)
            #pragma unroll
            for (int r = 0; r < 4; ++r) {
                const int row = rt*16 + quad*4 + r;
                #pragma unroll
                for (int ct = 0; ct < 4; ++ct)
                    Ob[(size_t)row*256 + cw + ct*16 + l16] = (bf16)o[rt*4 + ct][r];
            }
    }
}

// Sum the 2 or 3 partials of each split q-tile, normalize, write Ret.
__global__ __launch_bounds__(256) void combine_kernel(const bf16* __restrict__ Opart,
                                                      const float* __restrict__ Lpart,
                                                      bf16* __restrict__ Ret)
{
    const int bx = blockIdx.x;
    const int bh = bx / 21;
    const int ti = bx - bh*21;
    const int qt = 11 + ti;
    const int n  = (qt <= 21) ? 2 : 3;
    const int slotbase = (qt <= 21) ? (qt - 11)*2 : (22 + (qt - 22)*3);
    const size_t slot0 = (size_t)bh*52 + slotbase;
    const int b = bh >> 3, h = bh & 7;
    const int row  = threadIdx.x >> 2;
    const int col0 = (threadIdx.x & 3) * 64;

    float l = 0.f;
    for (int i = 0; i < n; ++i) l += Lpart[(slot0 + i)*64 + row];
    const float inv = 1.0f / l;

    const bf16* O0 = Opart + slot0 * (64*256) + (size_t)row*256 + col0;
    const int q = qt*64 + row;
    bf16* dst = Ret + ((size_t)b*S_LEN + q)*HDIM + h*DIM + col0;
    #pragma unroll
    for (int ch = 0; ch < 8; ++ch) {
        float acc[8] = {};
        for (int i = 0; i < n; ++i) {
            bf16x8 a = *(const bf16x8*)(O0 + (size_t)i*(64*256) + ch*8);
            #pragma unroll
            for (int j = 0; j < 8; ++j) acc[j] += (float)a[j];
        }
        bf16x8 w;
        #pragma unroll
        for (int j = 0; j < 8; ++j) w[j] = (bf16)(acc[j] * inv);
        *(bf16x8*)(dst + ch*8) = w;
    }
}

// ---------------------------------------------------------------------------

extern "C" void kernel_launch(void* const* d_in, const int* in_sizes, int n_in,
                              void* d_out, int out_size, void* d_ws, size_t ws_size,
                              hipStream_t stream)
{
    (void)in_sizes; (void)n_in; (void)out_size; (void)ws_size;
    const float* X  = (const float*)d_in[0];
    // d_in[1] timestamp, d_in[6] theta: dead code in reference output
    const float* wQ = (const float*)d_in[2];
    const float* wK = (const float*)d_in[3];
    const float* wV = (const float*)d_in[4];
    const float* wO = (const float*)d_in[5];

    char* ws = (char*)d_ws;
    const size_t MB = 1u << 20;
    bf16*  Xb    = (bf16*)(ws + 0*MB);    // [B,S,D]        2 MB
    bf16*  WQt   = (bf16*)(ws + 2*MB);    // [H,E,D]        1 MB
    bf16*  WKt   = (bf16*)(ws + 3*MB);
    bf16*  WVt   = (bf16*)(ws + 4*MB);
    bf16*  WOt   = (bf16*)(ws + 5*MB);    // [D,H*D]        1 MB
    bf16*  Qg    = (bf16*)(ws + 6*MB);    // [B,H,S,D]     16 MB (dead after attn)
    bf16*  Kg    = (bf16*)(ws + 22*MB);   // [B,H,S,D]     16 MB (dead after attn)
    bf16*  VTg   = (bf16*)(ws + 38*MB);   // [B,H,D,S]     16 MB
    bf16*  Ret   = (bf16*)(ws + 54*MB);   // [B,S,H*D]     16 MB
    bf16*  Opart = (bf16*)(ws + 70*MB);   // 832 slots x 64x256 bf16 = 27.25 MB
    float* Lpart = (float*)(ws + 98*MB);  // 832 x 64 fp32 = 208 KB
    float* slabs = (float*)Qg;            // reuse dead Qg+Kg: 8 x 4 MB fp32 = 32 MB

    prep_kernel    <<<dim3(4, 32, 5), 256, 0, stream>>>(X, wQ, wK, wV, wO,
                                                        Xb, WQt, WKt, WVt, WOt);
    proj_kernel    <<<dim3(16, 48), 512, 0, stream>>>(Xb, WQt, WKt, WVt, Qg, Kg, VTg);
    attn_kernel    <<<1008,         256, 0, stream>>>(Qg, Kg, VTg, Ret, Opart, Lpart);
    combine_kernel <<<336,          256, 0, stream>>>(Opart, Lpart, Ret);
    outproj_kernel <<<256,          512, 0, stream>>>(Ret, WOt, slabs);
    reduce_out_kernel<<<1024,       256, 0, stream>>>(slabs, (float*)d_out);
}